// Round 18
// baseline (1050.596 us; speedup 1.0000x reference)
//
#include <hip/hip_runtime.h>
#include <cstdint>

#define B_ 8
#define N_ 512
#define M_ 512
#define D_ 512
#define F_ 512
#define H_ 8
#define DH_ 64
#define FH_ 64

// ---- PROBE ROUND 3 (R16 structure): REP wrappers so each kernel exceeds the
// ~330us harness fills and surfaces in rocprof top-5. Outputs identical/rep.
#define REP_ATTN 4
#define REP_PV   16
#define REP_OUT  48

typedef __attribute__((ext_vector_type(8))) short bf16x8;
typedef __attribute__((ext_vector_type(4))) float f32x4;
typedef __attribute__((ext_vector_type(8))) unsigned short u16x8;

// RNE float -> bf16 bits, and back
__device__ __forceinline__ unsigned short f2bf(float x) {
    unsigned u = __float_as_uint(x);
    return (unsigned short)((u + 0x7fffu + ((u >> 16) & 1u)) >> 16);
}
__device__ __forceinline__ float bf2f(unsigned short b) {
    return __uint_as_float(((unsigned)b) << 16);
}

// Nontemporal loads via clang ext_vector_type.
__device__ __forceinline__ f32x4 ntload4(const float* p) {
    return __builtin_nontemporal_load((const f32x4*)p);
}
__device__ __forceinline__ float ntload1(const float* p) {
    return __builtin_nontemporal_load(p);
}

// DPP-based partial reduce (VALU pipe). bound_ctrl=true.
template <int CTRL>
__device__ __forceinline__ float dpp_add(float x) {
    int y = __builtin_amdgcn_update_dpp(0, __float_as_int(x), CTRL, 0xf, 0xf, true);
    return x + __int_as_float(y);
}

// K2 (fused K1): per (h,n): Q1 = gelu(X*diag(W1)); logits = Q1·W2^T; softmax;
// emit A as bf16 (hi only).
__global__ __launch_bounds__(256, 4) void syn_k_attn(const float* __restrict__ X,
                                                     const float* __restrict__ W1,
                                                     const float* __restrict__ W2,
                                                     unsigned short* __restrict__ Ahi) {
    int hn = blockIdx.x;
    int h = hn >> 9, n = hn & 511;
    int t = threadIdx.x;
    int wave = t >> 6, lane = t & 63;
    __shared__ float q1s[8 * 68];        // [b][d], stride 68
    __shared__ float logits[8 * 520];    // [b][m], stride 520

    #pragma unroll 1
    for (int rep = 0; rep < REP_ATTN; ++rep) {
        {
            int d = t & 63;
            int b0 = t >> 6;
            float w = ntload1(W1 + (size_t)hn * (DH_ * DH_) + d * (DH_ + 1));
            #pragma unroll
            for (int i = 0; i < 2; ++i) {
                int bi = b0 + i * 4;
                float x = X[((size_t)(bi * N_ + n)) * D_ + h * DH_ + d];
                float v = x * w;
                q1s[bi * 68 + d] = 0.5f * v * (1.0f + erff(v * 0.70710678118654752440f));
            }
        }
        __syncthreads();

        int mr = lane >> 3, c = lane & 7;
        float4 qa[8], qb[8];
        #pragma unroll
        for (int b = 0; b < 8; ++b) {
            qa[b] = *(const float4*)&q1s[b * 68 + c * 8];
            qb[b] = *(const float4*)&q1s[b * 68 + c * 8 + 4];
        }

        const float* w2 = W2 + (size_t)hn * ((size_t)M_ * DH_);
        #pragma unroll 4
        for (int g = 0; g < 16; ++g) {
            int m = (wave + g * 4) * 8 + mr;
            const float* wr = w2 + (size_t)m * DH_ + c * 8;
            f32x4 wa = ntload4(wr);
            f32x4 wb = ntload4(wr + 4);
            float acc[8];
            #pragma unroll
            for (int b = 0; b < 8; ++b) {
                float a0 = wa.x * qa[b].x + wa.y * qa[b].y + wa.z * qa[b].z + wa.w * qa[b].w
                         + wb.x * qb[b].x + wb.y * qb[b].y + wb.z * qb[b].z + wb.w * qb[b].w;
                a0 = dpp_add<0xB1>(a0);
                a0 = dpp_add<0x4E>(a0);
                a0 = dpp_add<0x124>(a0);
                acc[b] = a0;
            }
            float lo = c == 0 ? acc[0] : c == 1 ? acc[1] : c == 2 ? acc[2] : acc[3];
            float hi = c == 0 ? acc[4] : c == 1 ? acc[5] : c == 2 ? acc[6] : acc[7];
            if (c < 4) {
                logits[c * 520 + m] = lo;
                logits[(c + 4) * 520 + m] = hi;
            }
        }
        __syncthreads();

        for (int bb = wave; bb < 8; bb += 4) {
            const float* lrow = &logits[bb * 520 + lane * 8];
            float4 va = *(const float4*)lrow;
            float4 vb = *(const float4*)(lrow + 4);
            float v[8] = {va.x, va.y, va.z, va.w, vb.x, vb.y, vb.z, vb.w};
            float mx = v[0];
            #pragma unroll
            for (int i = 1; i < 8; ++i) mx = fmaxf(mx, v[i]);
            #pragma unroll
            for (int s = 1; s < 64; s <<= 1) mx = fmaxf(mx, __shfl_xor(mx, s));
            float e[8]; float sum = 0.f;
            #pragma unroll
            for (int i = 0; i < 8; ++i) { e[i] = expf(v[i] - mx); sum += e[i]; }
            #pragma unroll
            for (int s = 1; s < 64; s <<= 1) sum += __shfl_xor(sum, s);
            float inv = 1.0f / sum;
            unsigned short hb[8];
            #pragma unroll
            for (int i = 0; i < 8; ++i) hb[i] = f2bf(e[i] * inv);
            size_t base = ((size_t)(bb * H_ + h) * N_ + n) * M_ + lane * 8;
            *(u16x8*)(Ahi + base) = *(u16x8*)hb;
        }
        __syncthreads();
    }
}

// Split Ow into bf16 hi/lo arrays.
__global__ __launch_bounds__(256) void syn_k_splitw(const float* __restrict__ Ow,
                                                    unsigned short* __restrict__ Whi,
                                                    unsigned short* __restrict__ Wlo) {
    int i = (blockIdx.x * 256 + threadIdx.x) * 4;
    float4 v = *(const float4*)(Ow + i);
    float vv[4] = {v.x, v.y, v.z, v.w};
    unsigned short hb[4], lb[4];
    #pragma unroll
    for (int j = 0; j < 4; ++j) {
        hb[j] = f2bf(vv[j]);
        lb[j] = f2bf(vv[j] - bf2f(hb[j]));
    }
    uint2 hv, lv;
    hv.x = (unsigned)hb[0] | ((unsigned)hb[1] << 16);
    hv.y = (unsigned)hb[2] | ((unsigned)hb[3] << 16);
    lv.x = (unsigned)lb[0] | ((unsigned)lb[1] << 16);
    lv.y = (unsigned)lb[2] | ((unsigned)lb[3] << 16);
    *(uint2*)(Whi + i) = hv;
    *(uint2*)(Wlo + i) = lv;
}

// splitv: Vt_hi[(bh*64+f)*512 + m] = bf16(V[b][m][h*64+f]). LDS transpose.
__global__ __launch_bounds__(256) void syn_k_splitv(const float* __restrict__ V,
                                                    unsigned short* __restrict__ Vthi) {
    int bh = blockIdx.x;
    int b = bh >> 3, h = bh & 7;
    int t = threadIdx.x;
    __shared__ float lds[64 * 68];
    for (int m0 = 0; m0 < M_; m0 += 64) {
        int m = t >> 2, fo = (t & 3) * 16;
        const float* src = V + ((size_t)(b * M_ + m0 + m)) * F_ + h * FH_ + fo;
        #pragma unroll
        for (int i = 0; i < 4; ++i)
            *(float4*)&lds[m * 68 + fo + i * 4] = *(const float4*)(src + i * 4);
        __syncthreads();
        int f = t >> 2, mo = (t & 3) * 16;
        unsigned short hb[16];
        #pragma unroll
        for (int i = 0; i < 16; ++i)
            hb[i] = f2bf(lds[(mo + i) * 68 + f]);
        size_t base = ((size_t)(bh * 64 + f)) * 512 + m0 + mo;
        *(u16x8*)(Vthi + base) = *(u16x8*)hb;
        *(u16x8*)(Vthi + base + 8) = *(u16x8*)&hb[8];
        __syncthreads();
    }
}

// K3 (bf16 MFMA, single-term): Y[n,f] = (Σ_m A[n,m]·Vt[f,m])*WVdiag[f].
__global__ __launch_bounds__(256) void syn_k_pv_mfma(const unsigned short* __restrict__ Ahi,
                                                     const unsigned short* __restrict__ Vthi,
                                                     const float* __restrict__ WV,
                                                     unsigned short* __restrict__ Yhi,
                                                     unsigned short* __restrict__ Ylo) {
    int bh = blockIdx.y;
    int b = bh >> 3, h = bh & 7;
    int n0 = blockIdx.x * 32;
    int t = threadIdx.x;
    int lane = t & 63, wave = t >> 6;
    int wr = wave >> 1, wc = wave & 1;
    __shared__ __align__(16) unsigned short Alh[32 * 64];
    __shared__ __align__(16) unsigned short Blh[64 * 64];

    int srow = t >> 3, skg = t & 7;
    int sslot = skg ^ (srow & 7);
    const unsigned short* Ahb = Ahi + ((size_t)bh * N_ + n0) * M_;
    const unsigned short* Vhb = Vthi + ((size_t)bh * 64) * 512;

    #pragma unroll 1
    for (int rep = 0; rep < REP_PV; ++rep) {
        f32x4 acc[2];
        acc[0] = (f32x4){0.f, 0.f, 0.f, 0.f};
        acc[1] = (f32x4){0.f, 0.f, 0.f, 0.f};

        u16x8 rAh  = *(const u16x8*)(Ahb + (size_t)srow * M_ + skg * 8);
        u16x8 rBh0 = *(const u16x8*)(Vhb + (size_t)srow * 512 + skg * 8);
        u16x8 rBh1 = *(const u16x8*)(Vhb + (size_t)(srow + 32) * 512 + skg * 8);

        #pragma unroll 1
        for (int mb = 0; mb < 8; ++mb) {
            *(u16x8*)&Alh[srow * 64 + sslot * 8] = rAh;
            *(u16x8*)&Blh[srow * 64 + sslot * 8] = rBh0;
            *(u16x8*)&Blh[(srow + 32) * 64 + sslot * 8] = rBh1;
            __syncthreads();
            if (mb < 7) {
                int m0 = (mb + 1) * 64;
                rAh  = *(const u16x8*)(Ahb + (size_t)srow * M_ + m0 + skg * 8);
                rBh0 = *(const u16x8*)(Vhb + (size_t)srow * 512 + m0 + skg * 8);
                rBh1 = *(const u16x8*)(Vhb + (size_t)(srow + 32) * 512 + m0 + skg * 8);
            }
            #pragma unroll
            for (int mg = 0; mg < 2; ++mg) {
                int kslot = (mg * 4 + (lane >> 4)) ^ (lane & 7);
                int arow = wr * 16 + (lane & 15);
                bf16x8 afh = *(const bf16x8*)&Alh[arow * 64 + kslot * 8];
                #pragma unroll
                for (int j = 0; j < 2; ++j) {
                    int brow = wc * 32 + j * 16 + (lane & 15);
                    bf16x8 bfh = *(const bf16x8*)&Blh[brow * 64 + kslot * 8];
                    acc[j] = __builtin_amdgcn_mfma_f32_16x16x32_bf16(afh, bfh, acc[j], 0, 0, 0);
                }
            }
            __syncthreads();
        }

        int crow = n0 + wr * 16 + (lane >> 4) * 4;
        int ccol = wc * 32 + (lane & 15);
        #pragma unroll
        for (int j = 0; j < 2; ++j) {
            int f = ccol + j * 16;
            float s = WV[(size_t)h * (FH_ * FH_) + f * (FH_ + 1)];
            #pragma unroll
            for (int r = 0; r < 4; ++r) {
                int row = crow + r;
                float y = acc[j][r] * s;
                unsigned short hb = f2bf(y);
                unsigned short lb = f2bf(y - bf2f(hb));
                size_t base = ((size_t)(b * N_ + row)) * F_ + h * FH_ + f;
                Yhi[base] = hb;
                Ylo[base] = lb;
            }
        }
    }
}

// K4 (split-bf16 MFMA): out = Yhi·Whi^T + Yhi·Wlo^T + Ylo·Whi^T + Ob.
__global__ __launch_bounds__(256) void syn_k_out_mfma(const unsigned short* __restrict__ Yhi,
                                                      const unsigned short* __restrict__ Ylo,
                                                      const unsigned short* __restrict__ Whi,
                                                      const unsigned short* __restrict__ Wlo,
                                                      const float* __restrict__ Ob,
                                                      float* __restrict__ out) {
    int r0 = blockIdx.x * 64;
    int f0 = blockIdx.y * 64;
    int t = threadIdx.x;
    int lane = t & 63, wave = t >> 6;
    int wr = wave >> 1, wc = wave & 1;
    __shared__ __align__(16) unsigned short Alh[64 * 64], All[64 * 64];
    __shared__ __align__(16) unsigned short Blh[64 * 64], Bll[64 * 64];

    int srow = t >> 3, skg = t & 7;
    int sslot = skg ^ (srow & 7);

    #pragma unroll 1
    for (int rep = 0; rep < REP_OUT; ++rep) {
        f32x4 acc[2][2];
        #pragma unroll
        for (int i = 0; i < 2; ++i)
            #pragma unroll
            for (int j = 0; j < 2; ++j) acc[i][j] = (f32x4){0.f, 0.f, 0.f, 0.f};

        #pragma unroll 1
        for (int kb = 0; kb < 512; kb += 64) {
            #pragma unroll
            for (int rr = 0; rr < 2; ++rr) {
                int row = srow + rr * 32;
                size_t ya = (size_t)(r0 + row) * 512 + kb + skg * 8;
                size_t wa = (size_t)(f0 + row) * 512 + kb + skg * 8;
                *(u16x8*)&Alh[row * 64 + sslot * 8] = *(const u16x8*)(Yhi + ya);
                *(u16x8*)&All[row * 64 + sslot * 8] = *(const u16x8*)(Ylo + ya);
                *(u16x8*)&Blh[row * 64 + sslot * 8] = *(const u16x8*)(Whi + wa);
                *(u16x8*)&Bll[row * 64 + sslot * 8] = *(const u16x8*)(Wlo + wa);
            }
            __syncthreads();
            #pragma unroll
            for (int mg = 0; mg < 2; ++mg) {
                int kslot = (mg * 4 + (lane >> 4)) ^ (lane & 7);
                bf16x8 afh[2], afl[2], bfh[2], bfl[2];
                #pragma unroll
                for (int q = 0; q < 2; ++q) {
                    int arow = wr * 32 + q * 16 + (lane & 15);
                    afh[q] = *(const bf16x8*)&Alh[arow * 64 + kslot * 8];
                    afl[q] = *(const bf16x8*)&All[arow * 64 + kslot * 8];
                    int brow = wc * 32 + q * 16 + (lane & 15);
                    bfh[q] = *(const bf16x8*)&Blh[brow * 64 + kslot * 8];
                    bfl[q] = *(const bf16x8*)&Bll[brow * 64 + kslot * 8];
                }
                #pragma unroll
                for (int i = 0; i < 2; ++i)
                    #pragma unroll
                    for (int j = 0; j < 2; ++j) {
                        acc[i][j] = __builtin_amdgcn_mfma_f32_16x16x32_bf16(afh[i], bfh[j], acc[i][j], 0, 0, 0);
                        acc[i][j] = __builtin_amdgcn_mfma_f32_16x16x32_bf16(afh[i], bfl[j], acc[i][j], 0, 0, 0);
                        acc[i][j] = __builtin_amdgcn_mfma_f32_16x16x32_bf16(afl[i], bfh[j], acc[i][j], 0, 0, 0);
                    }
            }
            __syncthreads();
        }

        int crow = r0 + wr * 32 + (lane >> 4) * 4;
        int ccol = f0 + wc * 32 + (lane & 15);
        float ob0 = Ob[ccol], ob1 = Ob[ccol + 16];
        #pragma unroll
        for (int i = 0; i < 2; ++i)
            #pragma unroll
            for (int j = 0; j < 2; ++j) {
                float obv = (j == 0) ? ob0 : ob1;
                #pragma unroll
                for (int r = 0; r < 4; ++r) {
                    int row = crow + i * 16 + r;
                    out[(size_t)row * F_ + ccol + j * 16] = acc[i][j][r] + obv;
                }
            }
    }
}

extern "C" void kernel_launch(void* const* d_in, const int* in_sizes, int n_in,
                              void* d_out, int out_size, void* d_ws, size_t ws_size,
                              hipStream_t stream) {
    const float* X  = (const float*)d_in[0];
    const float* V  = (const float*)d_in[1];
    const float* W1 = (const float*)d_in[2];
    const float* W2 = (const float*)d_in[3];
    const float* WV = (const float*)d_in[4];
    const float* Ow = (const float*)d_in[5];
    const float* Ob = (const float*)d_in[6];
    float* out = (float*)d_out;

    unsigned short* Ahi = (unsigned short*)d_ws;                  // B*H*N*M u16
    unsigned short* Yhi = Ahi + (size_t)B_ * H_ * N_ * M_;
    unsigned short* Ylo = Yhi + (size_t)B_ * N_ * F_;
    unsigned short* Whi = Ylo + (size_t)B_ * N_ * F_;
    unsigned short* Wlo = Whi + (size_t)F_ * F_;
    unsigned short* Vthi = Wlo + (size_t)F_ * F_;

    syn_k_splitw<<<(F_ * F_) / (256 * 4), 256, 0, stream>>>(Ow, Whi, Wlo);
    syn_k_splitv<<<B_ * H_, 256, 0, stream>>>(V, Vthi);
    syn_k_attn<<<H_ * N_, 256, 0, stream>>>(X, W1, W2, Ahi);
    syn_k_pv_mfma<<<dim3(N_ / 32, B_ * H_), 256, 0, stream>>>(Ahi, Vthi, WV, Yhi, Ylo);
    syn_k_out_mfma<<<dim3((B_ * N_) / 64, F_ / 64), 256, 0, stream>>>(Yhi, Ylo, Whi, Wlo, Ob, out);
}

// Round 19
// 481.479 us; speedup vs baseline: 2.1820x; 2.1820x over previous
//
#include <hip/hip_runtime.h>
#include <cstdint>

#define B_ 8
#define N_ 512
#define M_ 512
#define D_ 512
#define F_ 512
#define H_ 8
#define DH_ 64
#define FH_ 64

typedef __attribute__((ext_vector_type(8))) short bf16x8;
typedef __attribute__((ext_vector_type(4))) float f32x4;
typedef __attribute__((ext_vector_type(8))) unsigned short u16x8;

// RNE float -> bf16 bits, and back
__device__ __forceinline__ unsigned short f2bf(float x) {
    unsigned u = __float_as_uint(x);
    return (unsigned short)((u + 0x7fffu + ((u >> 16) & 1u)) >> 16);
}
__device__ __forceinline__ float bf2f(unsigned short b) {
    return __uint_as_float(((unsigned)b) << 16);
}

// Nontemporal loads via clang ext_vector_type. Keep zero-reuse W2/W1 streams
// out of cache so A stays resident.
__device__ __forceinline__ f32x4 ntload4(const float* p) {
    return __builtin_nontemporal_load((const f32x4*)p);
}
__device__ __forceinline__ float ntload1(const float* p) {
    return __builtin_nontemporal_load(p);
}

// DPP-based partial reduce (VALU pipe). bound_ctrl=true.
template <int CTRL>
__device__ __forceinline__ float dpp_add(float x) {
    int y = __builtin_amdgcn_update_dpp(0, __float_as_int(x), CTRL, 0xf, 0xf, true);
    return x + __int_as_float(y);
}

// K2 (fused K1): per (h,n): Q1 = gelu(X*diag(W1)); logits = Q1·W2^T; softmax;
// emit A as bf16 (hi only). 8 blocks/CU (probe #3: 4 blocks/CU was
// latency-bound — hbm 31%, VALU 48%, occupancy 46%).
__global__ __launch_bounds__(256, 8) void syn_k_attn(const float* __restrict__ X,
                                                     const float* __restrict__ W1,
                                                     const float* __restrict__ W2,
                                                     unsigned short* __restrict__ Ahi) {
    int hn = blockIdx.x;
    int h = hn >> 9, n = hn & 511;
    int t = threadIdx.x;
    int wave = t >> 6, lane = t & 63;
    __shared__ float q1s[8 * 68];        // [b][d], stride 68
    __shared__ float logits[8 * 520];    // [b][m], stride 520

    {
        int d = t & 63;
        int b0 = t >> 6;
        float w = ntload1(W1 + (size_t)hn * (DH_ * DH_) + d * (DH_ + 1));
        #pragma unroll
        for (int i = 0; i < 2; ++i) {
            int bi = b0 + i * 4;
            float x = X[((size_t)(bi * N_ + n)) * D_ + h * DH_ + d];
            float v = x * w;
            q1s[bi * 68 + d] = 0.5f * v * (1.0f + erff(v * 0.70710678118654752440f));
        }
    }
    __syncthreads();

    int mr = lane >> 3, c = lane & 7;
    float4 qa[8], qb[8];
    #pragma unroll
    for (int b = 0; b < 8; ++b) {
        qa[b] = *(const float4*)&q1s[b * 68 + c * 8];
        qb[b] = *(const float4*)&q1s[b * 68 + c * 8 + 4];
    }

    const float* w2 = W2 + (size_t)hn * ((size_t)M_ * DH_);
    #pragma unroll 4
    for (int g = 0; g < 16; ++g) {
        int m = (wave + g * 4) * 8 + mr;
        const float* wr = w2 + (size_t)m * DH_ + c * 8;
        f32x4 wa = ntload4(wr);
        f32x4 wb = ntload4(wr + 4);
        float acc[8];
        #pragma unroll
        for (int b = 0; b < 8; ++b) {
            float a0 = wa.x * qa[b].x + wa.y * qa[b].y + wa.z * qa[b].z + wa.w * qa[b].w
                     + wb.x * qb[b].x + wb.y * qb[b].y + wb.z * qb[b].z + wb.w * qb[b].w;
            a0 = dpp_add<0xB1>(a0);    // + lane^1 (quad_perm)
            a0 = dpp_add<0x4E>(a0);    // + lane^2 (quad_perm)
            a0 = dpp_add<0x124>(a0);   // row_ror:4 — valid on (lane%16)<4 i.e. c<4
            acc[b] = a0;
        }
        float lo = c == 0 ? acc[0] : c == 1 ? acc[1] : c == 2 ? acc[2] : acc[3];
        float hi = c == 0 ? acc[4] : c == 1 ? acc[5] : c == 2 ? acc[6] : acc[7];
        if (c < 4) {
            logits[c * 520 + m] = lo;
            logits[(c + 4) * 520 + m] = hi;
        }
    }
    __syncthreads();

    for (int bb = wave; bb < 8; bb += 4) {
        const float* lrow = &logits[bb * 520 + lane * 8];
        float4 va = *(const float4*)lrow;
        float4 vb = *(const float4*)(lrow + 4);
        float v[8] = {va.x, va.y, va.z, va.w, vb.x, vb.y, vb.z, vb.w};
        float mx = v[0];
        #pragma unroll
        for (int i = 1; i < 8; ++i) mx = fmaxf(mx, v[i]);
        #pragma unroll
        for (int s = 1; s < 64; s <<= 1) mx = fmaxf(mx, __shfl_xor(mx, s));
        float e[8]; float sum = 0.f;
        #pragma unroll
        for (int i = 0; i < 8; ++i) { e[i] = expf(v[i] - mx); sum += e[i]; }
        #pragma unroll
        for (int s = 1; s < 64; s <<= 1) sum += __shfl_xor(sum, s);
        float inv = 1.0f / sum;
        unsigned short hb[8];
        #pragma unroll
        for (int i = 0; i < 8; ++i) hb[i] = f2bf(e[i] * inv);
        size_t base = ((size_t)(bb * H_ + h) * N_ + n) * M_ + lane * 8;
        *(u16x8*)(Ahi + base) = *(u16x8*)hb;
    }
}

// Split Ow into bf16 hi/lo arrays. 512*512 elems, 4/thread, grid 256.
__global__ __launch_bounds__(256) void syn_k_splitw(const float* __restrict__ Ow,
                                                    unsigned short* __restrict__ Whi,
                                                    unsigned short* __restrict__ Wlo) {
    int i = (blockIdx.x * 256 + threadIdx.x) * 4;
    float4 v = *(const float4*)(Ow + i);
    float vv[4] = {v.x, v.y, v.z, v.w};
    unsigned short hb[4], lb[4];
    #pragma unroll
    for (int j = 0; j < 4; ++j) {
        hb[j] = f2bf(vv[j]);
        lb[j] = f2bf(vv[j] - bf2f(hb[j]));
    }
    uint2 hv, lv;
    hv.x = (unsigned)hb[0] | ((unsigned)hb[1] << 16);
    hv.y = (unsigned)hb[2] | ((unsigned)hb[3] << 16);
    lv.x = (unsigned)lb[0] | ((unsigned)lb[1] << 16);
    lv.y = (unsigned)lb[2] | ((unsigned)lb[3] << 16);
    *(uint2*)(Whi + i) = hv;
    *(uint2*)(Wlo + i) = lv;
}

// splitv: Vt_hi[(bh*64+f)*512 + m] = bf16(V[b][m][h*64+f]). LDS transpose.
__global__ __launch_bounds__(256) void syn_k_splitv(const float* __restrict__ V,
                                                    unsigned short* __restrict__ Vthi) {
    int bh = blockIdx.x;
    int b = bh >> 3, h = bh & 7;
    int t = threadIdx.x;
    __shared__ float lds[64 * 68];
    for (int m0 = 0; m0 < M_; m0 += 64) {
        int m = t >> 2, fo = (t & 3) * 16;
        const float* src = V + ((size_t)(b * M_ + m0 + m)) * F_ + h * FH_ + fo;
        #pragma unroll
        for (int i = 0; i < 4; ++i)
            *(float4*)&lds[m * 68 + fo + i * 4] = *(const float4*)(src + i * 4);
        __syncthreads();
        int f = t >> 2, mo = (t & 3) * 16;
        unsigned short hb[16];
        #pragma unroll
        for (int i = 0; i < 16; ++i)
            hb[i] = f2bf(lds[(mo + i) * 68 + f]);
        size_t base = ((size_t)(bh * 64 + f)) * 512 + m0 + mo;
        *(u16x8*)(Vthi + base) = *(u16x8*)hb;
        *(u16x8*)(Vthi + base + 8) = *(u16x8*)&hb[8];
        __syncthreads();
    }
}

// K3 (bf16 MFMA, single-term): Y[n,f] = (Σ_m A[n,m]·Vt[f,m])*WVdiag[f].
// 32x64 tile, LDS-staged, register prefetch. Y emitted split-bf16 for K4.
__global__ __launch_bounds__(256) void syn_k_pv_mfma(const unsigned short* __restrict__ Ahi,
                                                     const unsigned short* __restrict__ Vthi,
                                                     const float* __restrict__ WV,
                                                     unsigned short* __restrict__ Yhi,
                                                     unsigned short* __restrict__ Ylo) {
    int bh = blockIdx.y;
    int b = bh >> 3, h = bh & 7;
    int n0 = blockIdx.x * 32;
    int t = threadIdx.x;
    int lane = t & 63, wave = t >> 6;
    int wr = wave >> 1, wc = wave & 1;
    __shared__ __align__(16) unsigned short Alh[32 * 64];
    __shared__ __align__(16) unsigned short Blh[64 * 64];
    f32x4 acc[2];
    acc[0] = (f32x4){0.f, 0.f, 0.f, 0.f};
    acc[1] = (f32x4){0.f, 0.f, 0.f, 0.f};

    int srow = t >> 3, skg = t & 7;
    int sslot = skg ^ (srow & 7);
    const unsigned short* Ahb = Ahi + ((size_t)bh * N_ + n0) * M_;
    const unsigned short* Vhb = Vthi + ((size_t)bh * 64) * 512;

    u16x8 rAh, rBh0, rBh1;
    {
        rAh  = *(const u16x8*)(Ahb + (size_t)srow * M_ + skg * 8);
        rBh0 = *(const u16x8*)(Vhb + (size_t)srow * 512 + skg * 8);
        rBh1 = *(const u16x8*)(Vhb + (size_t)(srow + 32) * 512 + skg * 8);
    }

    #pragma unroll 1
    for (int mb = 0; mb < 8; ++mb) {
        *(u16x8*)&Alh[srow * 64 + sslot * 8] = rAh;
        *(u16x8*)&Blh[srow * 64 + sslot * 8] = rBh0;
        *(u16x8*)&Blh[(srow + 32) * 64 + sslot * 8] = rBh1;
        __syncthreads();
        if (mb < 7) {
            int m0 = (mb + 1) * 64;
            rAh  = *(const u16x8*)(Ahb + (size_t)srow * M_ + m0 + skg * 8);
            rBh0 = *(const u16x8*)(Vhb + (size_t)srow * 512 + m0 + skg * 8);
            rBh1 = *(const u16x8*)(Vhb + (size_t)(srow + 32) * 512 + m0 + skg * 8);
        }
        #pragma unroll
        for (int mg = 0; mg < 2; ++mg) {
            int kslot = (mg * 4 + (lane >> 4)) ^ (lane & 7);
            int arow = wr * 16 + (lane & 15);
            bf16x8 afh = *(const bf16x8*)&Alh[arow * 64 + kslot * 8];
            #pragma unroll
            for (int j = 0; j < 2; ++j) {
                int brow = wc * 32 + j * 16 + (lane & 15);
                bf16x8 bfh = *(const bf16x8*)&Blh[brow * 64 + kslot * 8];
                acc[j] = __builtin_amdgcn_mfma_f32_16x16x32_bf16(afh, bfh, acc[j], 0, 0, 0);
            }
        }
        __syncthreads();
    }

    int crow = n0 + wr * 16 + (lane >> 4) * 4;
    int ccol = wc * 32 + (lane & 15);
    #pragma unroll
    for (int j = 0; j < 2; ++j) {
        int f = ccol + j * 16;
        float s = WV[(size_t)h * (FH_ * FH_) + f * (FH_ + 1)];
        #pragma unroll
        for (int r = 0; r < 4; ++r) {
            int row = crow + r;
            float y = acc[j][r] * s;
            unsigned short hb = f2bf(y);
            unsigned short lb = f2bf(y - bf2f(hb));
            size_t base = ((size_t)(b * N_ + row)) * F_ + h * FH_ + f;
            Yhi[base] = hb;
            Ylo[base] = lb;
        }
    }
}

// K4 (split-bf16 MFMA): out = Yhi·Whi^T + Yhi·Wlo^T + Ylo·Whi^T + Ob.
__global__ __launch_bounds__(256) void syn_k_out_mfma(const unsigned short* __restrict__ Yhi,
                                                      const unsigned short* __restrict__ Ylo,
                                                      const unsigned short* __restrict__ Whi,
                                                      const unsigned short* __restrict__ Wlo,
                                                      const float* __restrict__ Ob,
                                                      float* __restrict__ out) {
    int r0 = blockIdx.x * 64;
    int f0 = blockIdx.y * 64;
    int t = threadIdx.x;
    int lane = t & 63, wave = t >> 6;
    int wr = wave >> 1, wc = wave & 1;
    __shared__ __align__(16) unsigned short Alh[64 * 64], All[64 * 64];
    __shared__ __align__(16) unsigned short Blh[64 * 64], Bll[64 * 64];
    f32x4 acc[2][2];
    #pragma unroll
    for (int i = 0; i < 2; ++i)
        #pragma unroll
        for (int j = 0; j < 2; ++j) acc[i][j] = (f32x4){0.f, 0.f, 0.f, 0.f};

    int srow = t >> 3, skg = t & 7;
    int sslot = skg ^ (srow & 7);

    #pragma unroll 1
    for (int kb = 0; kb < 512; kb += 64) {
        #pragma unroll
        for (int rr = 0; rr < 2; ++rr) {
            int row = srow + rr * 32;
            size_t ya = (size_t)(r0 + row) * 512 + kb + skg * 8;
            size_t wa = (size_t)(f0 + row) * 512 + kb + skg * 8;
            *(u16x8*)&Alh[row * 64 + sslot * 8] = *(const u16x8*)(Yhi + ya);
            *(u16x8*)&All[row * 64 + sslot * 8] = *(const u16x8*)(Ylo + ya);
            *(u16x8*)&Blh[row * 64 + sslot * 8] = *(const u16x8*)(Whi + wa);
            *(u16x8*)&Bll[row * 64 + sslot * 8] = *(const u16x8*)(Wlo + wa);
        }
        __syncthreads();
        #pragma unroll
        for (int mg = 0; mg < 2; ++mg) {
            int kslot = (mg * 4 + (lane >> 4)) ^ (lane & 7);
            bf16x8 afh[2], afl[2], bfh[2], bfl[2];
            #pragma unroll
            for (int q = 0; q < 2; ++q) {
                int arow = wr * 32 + q * 16 + (lane & 15);
                afh[q] = *(const bf16x8*)&Alh[arow * 64 + kslot * 8];
                afl[q] = *(const bf16x8*)&All[arow * 64 + kslot * 8];
                int brow = wc * 32 + q * 16 + (lane & 15);
                bfh[q] = *(const bf16x8*)&Blh[brow * 64 + kslot * 8];
                bfl[q] = *(const bf16x8*)&Bll[brow * 64 + kslot * 8];
            }
            #pragma unroll
            for (int i = 0; i < 2; ++i)
                #pragma unroll
                for (int j = 0; j < 2; ++j) {
                    acc[i][j] = __builtin_amdgcn_mfma_f32_16x16x32_bf16(afh[i], bfh[j], acc[i][j], 0, 0, 0);
                    acc[i][j] = __builtin_amdgcn_mfma_f32_16x16x32_bf16(afh[i], bfl[j], acc[i][j], 0, 0, 0);
                    acc[i][j] = __builtin_amdgcn_mfma_f32_16x16x32_bf16(afl[i], bfh[j], acc[i][j], 0, 0, 0);
                }
        }
        __syncthreads();
    }

    int crow = r0 + wr * 32 + (lane >> 4) * 4;
    int ccol = f0 + wc * 32 + (lane & 15);
    float ob0 = Ob[ccol], ob1 = Ob[ccol + 16];
    #pragma unroll
    for (int i = 0; i < 2; ++i)
        #pragma unroll
        for (int j = 0; j < 2; ++j) {
            float obv = (j == 0) ? ob0 : ob1;
            #pragma unroll
            for (int r = 0; r < 4; ++r) {
                int row = crow + i * 16 + r;
                out[(size_t)row * F_ + ccol + j * 16] = acc[i][j][r] + obv;
            }
        }
}

extern "C" void kernel_launch(void* const* d_in, const int* in_sizes, int n_in,
                              void* d_out, int out_size, void* d_ws, size_t ws_size,
                              hipStream_t stream) {
    const float* X  = (const float*)d_in[0];
    const float* V  = (const float*)d_in[1];
    const float* W1 = (const float*)d_in[2];
    const float* W2 = (const float*)d_in[3];
    const float* WV = (const float*)d_in[4];
    const float* Ow = (const float*)d_in[5];
    const float* Ob = (const float*)d_in[6];
    float* out = (float*)d_out;

    unsigned short* Ahi = (unsigned short*)d_ws;                  // B*H*N*M u16
    unsigned short* Yhi = Ahi + (size_t)B_ * H_ * N_ * M_;
    unsigned short* Ylo = Yhi + (size_t)B_ * N_ * F_;
    unsigned short* Whi = Ylo + (size_t)B_ * N_ * F_;
    unsigned short* Wlo = Whi + (size_t)F_ * F_;
    unsigned short* Vthi = Wlo + (size_t)F_ * F_;

    syn_k_splitw<<<(F_ * F_) / (256 * 4), 256, 0, stream>>>(Ow, Whi, Wlo);
    syn_k_splitv<<<B_ * H_, 256, 0, stream>>>(V, Vthi);
    syn_k_attn<<<H_ * N_, 256, 0, stream>>>(X, W1, W2, Ahi);
    syn_k_pv_mfma<<<dim3(N_ / 32, B_ * H_), 256, 0, stream>>>(Ahi, Vthi, WV, Yhi, Ylo);
    syn_k_out_mfma<<<dim3((B_ * N_) / 64, F_ / 64), 256, 0, stream>>>(Yhi, Ylo, Whi, Wlo, Ob, out);
}

// Round 20
// 169.139 us; speedup vs baseline: 6.2114x; 2.8466x over previous
//
#include <hip/hip_runtime.h>
#include <cstdint>

#define B_ 8
#define N_ 512
#define M_ 512
#define D_ 512
#define F_ 512
#define H_ 8
#define DH_ 64
#define FH_ 64

typedef __attribute__((ext_vector_type(8))) short bf16x8;
typedef __attribute__((ext_vector_type(4))) float f32x4;
typedef __attribute__((ext_vector_type(8))) unsigned short u16x8;

// RNE float -> bf16 bits, and back
__device__ __forceinline__ unsigned short f2bf(float x) {
    unsigned u = __float_as_uint(x);
    return (unsigned short)((u + 0x7fffu + ((u >> 16) & 1u)) >> 16);
}
__device__ __forceinline__ float bf2f(unsigned short b) {
    return __uint_as_float(((unsigned)b) << 16);
}

// Nontemporal loads via clang ext_vector_type. Keep zero-reuse W2/W1 streams
// out of cache so A stays resident.
__device__ __forceinline__ f32x4 ntload4(const float* p) {
    return __builtin_nontemporal_load((const f32x4*)p);
}
__device__ __forceinline__ float ntload1(const float* p) {
    return __builtin_nontemporal_load(p);
}

// DPP-based partial reduce (VALU pipe). bound_ctrl=true.
template <int CTRL>
__device__ __forceinline__ float dpp_add(float x) {
    int y = __builtin_amdgcn_update_dpp(0, __float_as_int(x), CTRL, 0xf, 0xf, true);
    return x + __int_as_float(y);
}

// K2 (fused K1): per (h,n): Q1 = gelu(X*diag(W1)); logits = Q1·W2^T; softmax;
// emit A as bf16 (hi only). 4 blocks/CU (R19: forcing 8 collapsed VGPR to 32
// and spilled — 2.8x regression); unroll 8 deepens the nt-load pipeline
// (probe #3: attn at 70% of achievable BW, ~2KB/CU in flight vs ~5KB needed).
__global__ __launch_bounds__(256, 4) void syn_k_attn(const float* __restrict__ X,
                                                     const float* __restrict__ W1,
                                                     const float* __restrict__ W2,
                                                     unsigned short* __restrict__ Ahi) {
    int hn = blockIdx.x;
    int h = hn >> 9, n = hn & 511;
    int t = threadIdx.x;
    int wave = t >> 6, lane = t & 63;
    __shared__ float q1s[8 * 68];        // [b][d], stride 68
    __shared__ float logits[8 * 520];    // [b][m], stride 520

    {
        int d = t & 63;
        int b0 = t >> 6;
        float w = ntload1(W1 + (size_t)hn * (DH_ * DH_) + d * (DH_ + 1));
        #pragma unroll
        for (int i = 0; i < 2; ++i) {
            int bi = b0 + i * 4;
            float x = X[((size_t)(bi * N_ + n)) * D_ + h * DH_ + d];
            float v = x * w;
            q1s[bi * 68 + d] = 0.5f * v * (1.0f + erff(v * 0.70710678118654752440f));
        }
    }
    __syncthreads();

    int mr = lane >> 3, c = lane & 7;
    float4 qa[8], qb[8];
    #pragma unroll
    for (int b = 0; b < 8; ++b) {
        qa[b] = *(const float4*)&q1s[b * 68 + c * 8];
        qb[b] = *(const float4*)&q1s[b * 68 + c * 8 + 4];
    }

    const float* w2 = W2 + (size_t)hn * ((size_t)M_ * DH_);
    #pragma unroll 8
    for (int g = 0; g < 16; ++g) {
        int m = (wave + g * 4) * 8 + mr;
        const float* wr = w2 + (size_t)m * DH_ + c * 8;
        f32x4 wa = ntload4(wr);
        f32x4 wb = ntload4(wr + 4);
        float acc[8];
        #pragma unroll
        for (int b = 0; b < 8; ++b) {
            float a0 = wa.x * qa[b].x + wa.y * qa[b].y + wa.z * qa[b].z + wa.w * qa[b].w
                     + wb.x * qb[b].x + wb.y * qb[b].y + wb.z * qb[b].z + wb.w * qb[b].w;
            a0 = dpp_add<0xB1>(a0);    // + lane^1 (quad_perm)
            a0 = dpp_add<0x4E>(a0);    // + lane^2 (quad_perm)
            a0 = dpp_add<0x124>(a0);   // row_ror:4 — valid on (lane%16)<4 i.e. c<4
            acc[b] = a0;
        }
        float lo = c == 0 ? acc[0] : c == 1 ? acc[1] : c == 2 ? acc[2] : acc[3];
        float hi = c == 0 ? acc[4] : c == 1 ? acc[5] : c == 2 ? acc[6] : acc[7];
        if (c < 4) {
            logits[c * 520 + m] = lo;
            logits[(c + 4) * 520 + m] = hi;
        }
    }
    __syncthreads();

    for (int bb = wave; bb < 8; bb += 4) {
        const float* lrow = &logits[bb * 520 + lane * 8];
        float4 va = *(const float4*)lrow;
        float4 vb = *(const float4*)(lrow + 4);
        float v[8] = {va.x, va.y, va.z, va.w, vb.x, vb.y, vb.z, vb.w};
        float mx = v[0];
        #pragma unroll
        for (int i = 1; i < 8; ++i) mx = fmaxf(mx, v[i]);
        #pragma unroll
        for (int s = 1; s < 64; s <<= 1) mx = fmaxf(mx, __shfl_xor(mx, s));
        float e[8]; float sum = 0.f;
        #pragma unroll
        for (int i = 0; i < 8; ++i) { e[i] = expf(v[i] - mx); sum += e[i]; }
        #pragma unroll
        for (int s = 1; s < 64; s <<= 1) sum += __shfl_xor(sum, s);
        float inv = 1.0f / sum;
        unsigned short hb[8];
        #pragma unroll
        for (int i = 0; i < 8; ++i) hb[i] = f2bf(e[i] * inv);
        size_t base = ((size_t)(bb * H_ + h) * N_ + n) * M_ + lane * 8;
        *(u16x8*)(Ahi + base) = *(u16x8*)hb;
    }
}

// Split Ow into bf16 hi/lo arrays. 512*512 elems, 4/thread, grid 256.
__global__ __launch_bounds__(256) void syn_k_splitw(const float* __restrict__ Ow,
                                                    unsigned short* __restrict__ Whi,
                                                    unsigned short* __restrict__ Wlo) {
    int i = (blockIdx.x * 256 + threadIdx.x) * 4;
    float4 v = *(const float4*)(Ow + i);
    float vv[4] = {v.x, v.y, v.z, v.w};
    unsigned short hb[4], lb[4];
    #pragma unroll
    for (int j = 0; j < 4; ++j) {
        hb[j] = f2bf(vv[j]);
        lb[j] = f2bf(vv[j] - bf2f(hb[j]));
    }
    uint2 hv, lv;
    hv.x = (unsigned)hb[0] | ((unsigned)hb[1] << 16);
    hv.y = (unsigned)hb[2] | ((unsigned)hb[3] << 16);
    lv.x = (unsigned)lb[0] | ((unsigned)lb[1] << 16);
    lv.y = (unsigned)lb[2] | ((unsigned)lb[3] << 16);
    *(uint2*)(Whi + i) = hv;
    *(uint2*)(Wlo + i) = lv;
}

// splitv: Vt_hi[(bh*64+f)*512 + m] = bf16(V[b][m][h*64+f]). LDS transpose.
__global__ __launch_bounds__(256) void syn_k_splitv(const float* __restrict__ V,
                                                    unsigned short* __restrict__ Vthi) {
    int bh = blockIdx.x;
    int b = bh >> 3, h = bh & 7;
    int t = threadIdx.x;
    __shared__ float lds[64 * 68];
    for (int m0 = 0; m0 < M_; m0 += 64) {
        int m = t >> 2, fo = (t & 3) * 16;
        const float* src = V + ((size_t)(b * M_ + m0 + m)) * F_ + h * FH_ + fo;
        #pragma unroll
        for (int i = 0; i < 4; ++i)
            *(float4*)&lds[m * 68 + fo + i * 4] = *(const float4*)(src + i * 4);
        __syncthreads();
        int f = t >> 2, mo = (t & 3) * 16;
        unsigned short hb[16];
        #pragma unroll
        for (int i = 0; i < 16; ++i)
            hb[i] = f2bf(lds[(mo + i) * 68 + f]);
        size_t base = ((size_t)(bh * 64 + f)) * 512 + m0 + mo;
        *(u16x8*)(Vthi + base) = *(u16x8*)hb;
        *(u16x8*)(Vthi + base + 8) = *(u16x8*)&hb[8];
        __syncthreads();
    }
}

// K3 (bf16 MFMA, single-term): Y[n,f] = (Σ_m A[n,m]·Vt[f,m])*WVdiag[f].
// 32x64 tile, LDS-staged, register prefetch. Y emitted split-bf16 for K4.
__global__ __launch_bounds__(256) void syn_k_pv_mfma(const unsigned short* __restrict__ Ahi,
                                                     const unsigned short* __restrict__ Vthi,
                                                     const float* __restrict__ WV,
                                                     unsigned short* __restrict__ Yhi,
                                                     unsigned short* __restrict__ Ylo) {
    int bh = blockIdx.y;
    int b = bh >> 3, h = bh & 7;
    int n0 = blockIdx.x * 32;
    int t = threadIdx.x;
    int lane = t & 63, wave = t >> 6;
    int wr = wave >> 1, wc = wave & 1;
    __shared__ __align__(16) unsigned short Alh[32 * 64];
    __shared__ __align__(16) unsigned short Blh[64 * 64];
    f32x4 acc[2];
    acc[0] = (f32x4){0.f, 0.f, 0.f, 0.f};
    acc[1] = (f32x4){0.f, 0.f, 0.f, 0.f};

    int srow = t >> 3, skg = t & 7;
    int sslot = skg ^ (srow & 7);
    const unsigned short* Ahb = Ahi + ((size_t)bh * N_ + n0) * M_;
    const unsigned short* Vhb = Vthi + ((size_t)bh * 64) * 512;

    u16x8 rAh, rBh0, rBh1;
    {
        rAh  = *(const u16x8*)(Ahb + (size_t)srow * M_ + skg * 8);
        rBh0 = *(const u16x8*)(Vhb + (size_t)srow * 512 + skg * 8);
        rBh1 = *(const u16x8*)(Vhb + (size_t)(srow + 32) * 512 + skg * 8);
    }

    #pragma unroll 1
    for (int mb = 0; mb < 8; ++mb) {
        *(u16x8*)&Alh[srow * 64 + sslot * 8] = rAh;
        *(u16x8*)&Blh[srow * 64 + sslot * 8] = rBh0;
        *(u16x8*)&Blh[(srow + 32) * 64 + sslot * 8] = rBh1;
        __syncthreads();
        if (mb < 7) {
            int m0 = (mb + 1) * 64;
            rAh  = *(const u16x8*)(Ahb + (size_t)srow * M_ + m0 + skg * 8);
            rBh0 = *(const u16x8*)(Vhb + (size_t)srow * 512 + m0 + skg * 8);
            rBh1 = *(const u16x8*)(Vhb + (size_t)(srow + 32) * 512 + m0 + skg * 8);
        }
        #pragma unroll
        for (int mg = 0; mg < 2; ++mg) {
            int kslot = (mg * 4 + (lane >> 4)) ^ (lane & 7);
            int arow = wr * 16 + (lane & 15);
            bf16x8 afh = *(const bf16x8*)&Alh[arow * 64 + kslot * 8];
            #pragma unroll
            for (int j = 0; j < 2; ++j) {
                int brow = wc * 32 + j * 16 + (lane & 15);
                bf16x8 bfh = *(const bf16x8*)&Blh[brow * 64 + kslot * 8];
                acc[j] = __builtin_amdgcn_mfma_f32_16x16x32_bf16(afh, bfh, acc[j], 0, 0, 0);
            }
        }
        __syncthreads();
    }

    int crow = n0 + wr * 16 + (lane >> 4) * 4;
    int ccol = wc * 32 + (lane & 15);
    #pragma unroll
    for (int j = 0; j < 2; ++j) {
        int f = ccol + j * 16;
        float s = WV[(size_t)h * (FH_ * FH_) + f * (FH_ + 1)];
        #pragma unroll
        for (int r = 0; r < 4; ++r) {
            int row = crow + r;
            float y = acc[j][r] * s;
            unsigned short hb = f2bf(y);
            unsigned short lb = f2bf(y - bf2f(hb));
            size_t base = ((size_t)(b * N_ + row)) * F_ + h * FH_ + f;
            Yhi[base] = hb;
            Ylo[base] = lb;
        }
    }
}

// K4 (split-bf16 MFMA): out = Yhi·Whi^T + Yhi·Wlo^T + Ylo·Whi^T + Ob.
__global__ __launch_bounds__(256) void syn_k_out_mfma(const unsigned short* __restrict__ Yhi,
                                                      const unsigned short* __restrict__ Ylo,
                                                      const unsigned short* __restrict__ Whi,
                                                      const unsigned short* __restrict__ Wlo,
                                                      const float* __restrict__ Ob,
                                                      float* __restrict__ out) {
    int r0 = blockIdx.x * 64;
    int f0 = blockIdx.y * 64;
    int t = threadIdx.x;
    int lane = t & 63, wave = t >> 6;
    int wr = wave >> 1, wc = wave & 1;
    __shared__ __align__(16) unsigned short Alh[64 * 64], All[64 * 64];
    __shared__ __align__(16) unsigned short Blh[64 * 64], Bll[64 * 64];
    f32x4 acc[2][2];
    #pragma unroll
    for (int i = 0; i < 2; ++i)
        #pragma unroll
        for (int j = 0; j < 2; ++j) acc[i][j] = (f32x4){0.f, 0.f, 0.f, 0.f};

    int srow = t >> 3, skg = t & 7;
    int sslot = skg ^ (srow & 7);

    #pragma unroll 1
    for (int kb = 0; kb < 512; kb += 64) {
        #pragma unroll
        for (int rr = 0; rr < 2; ++rr) {
            int row = srow + rr * 32;
            size_t ya = (size_t)(r0 + row) * 512 + kb + skg * 8;
            size_t wa = (size_t)(f0 + row) * 512 + kb + skg * 8;
            *(u16x8*)&Alh[row * 64 + sslot * 8] = *(const u16x8*)(Yhi + ya);
            *(u16x8*)&All[row * 64 + sslot * 8] = *(const u16x8*)(Ylo + ya);
            *(u16x8*)&Blh[row * 64 + sslot * 8] = *(const u16x8*)(Whi + wa);
            *(u16x8*)&Bll[row * 64 + sslot * 8] = *(const u16x8*)(Wlo + wa);
        }
        __syncthreads();
        #pragma unroll
        for (int mg = 0; mg < 2; ++mg) {
            int kslot = (mg * 4 + (lane >> 4)) ^ (lane & 7);
            bf16x8 afh[2], afl[2], bfh[2], bfl[2];
            #pragma unroll
            for (int q = 0; q < 2; ++q) {
                int arow = wr * 32 + q * 16 + (lane & 15);
                afh[q] = *(const bf16x8*)&Alh[arow * 64 + kslot * 8];
                afl[q] = *(const bf16x8*)&All[arow * 64 + kslot * 8];
                int brow = wc * 32 + q * 16 + (lane & 15);
                bfh[q] = *(const bf16x8*)&Blh[brow * 64 + kslot * 8];
                bfl[q] = *(const bf16x8*)&Bll[brow * 64 + kslot * 8];
            }
            #pragma unroll
            for (int i = 0; i < 2; ++i)
                #pragma unroll
                for (int j = 0; j < 2; ++j) {
                    acc[i][j] = __builtin_amdgcn_mfma_f32_16x16x32_bf16(afh[i], bfh[j], acc[i][j], 0, 0, 0);
                    acc[i][j] = __builtin_amdgcn_mfma_f32_16x16x32_bf16(afh[i], bfl[j], acc[i][j], 0, 0, 0);
                    acc[i][j] = __builtin_amdgcn_mfma_f32_16x16x32_bf16(afl[i], bfh[j], acc[i][j], 0, 0, 0);
                }
        }
        __syncthreads();
    }

    int crow = r0 + wr * 32 + (lane >> 4) * 4;
    int ccol = f0 + wc * 32 + (lane & 15);
    float ob0 = Ob[ccol], ob1 = Ob[ccol + 16];
    #pragma unroll
    for (int i = 0; i < 2; ++i)
        #pragma unroll
        for (int j = 0; j < 2; ++j) {
            float obv = (j == 0) ? ob0 : ob1;
            #pragma unroll
            for (int r = 0; r < 4; ++r) {
                int row = crow + i * 16 + r;
                out[(size_t)row * F_ + ccol + j * 16] = acc[i][j][r] + obv;
            }
        }
}

extern "C" void kernel_launch(void* const* d_in, const int* in_sizes, int n_in,
                              void* d_out, int out_size, void* d_ws, size_t ws_size,
                              hipStream_t stream) {
    const float* X  = (const float*)d_in[0];
    const float* V  = (const float*)d_in[1];
    const float* W1 = (const float*)d_in[2];
    const float* W2 = (const float*)d_in[3];
    const float* WV = (const float*)d_in[4];
    const float* Ow = (const float*)d_in[5];
    const float* Ob = (const float*)d_in[6];
    float* out = (float*)d_out;

    unsigned short* Ahi = (unsigned short*)d_ws;                  // B*H*N*M u16
    unsigned short* Yhi = Ahi + (size_t)B_ * H_ * N_ * M_;
    unsigned short* Ylo = Yhi + (size_t)B_ * N_ * F_;
    unsigned short* Whi = Ylo + (size_t)B_ * N_ * F_;
    unsigned short* Wlo = Whi + (size_t)F_ * F_;
    unsigned short* Vthi = Wlo + (size_t)F_ * F_;

    syn_k_splitw<<<(F_ * F_) / (256 * 4), 256, 0, stream>>>(Ow, Whi, Wlo);
    syn_k_splitv<<<B_ * H_, 256, 0, stream>>>(V, Vthi);
    syn_k_attn<<<H_ * N_, 256, 0, stream>>>(X, W1, W2, Ahi);
    syn_k_pv_mfma<<<dim3(N_ / 32, B_ * H_), 256, 0, stream>>>(Ahi, Vthi, WV, Yhi, Ylo);
    syn_k_out_mfma<<<dim3((B_ * N_) / 64, F_ / 64), 256, 0, stream>>>(Yhi, Ylo, Whi, Wlo, Ob, out);
}